// Round 3
// 3068.412 us; speedup vs baseline: 2.3726x; 2.3726x over previous
//
#include <hip/hip_runtime.h>
#include <math.h>

// Problem constants (match reference setup_inputs)
#define N_NODES   50000
#define N_EDGES   800000
#define IN_DIM    3703
#define HIDDEN    500
#define N_CLASSES 6
#define HP        512      // padded hidden stride (mult of 128)
#define KP1       3712     // IN_DIM padded to mult of 32

typedef float f32x4 __attribute__((ext_vector_type(4)));
typedef short s16x8 __attribute__((ext_vector_type(8)));

__device__ __forceinline__ unsigned short f2bf(float f) {
    union { float f; unsigned u; } v; v.f = f;
    unsigned r = v.u + 0x7fffu + ((v.u >> 16) & 1u);   // RNE
    return (unsigned short)(r >> 16);
}
__device__ __forceinline__ float bflo(unsigned p) { return __uint_as_float(p << 16); }
__device__ __forceinline__ float bfhi(unsigned p) { return __uint_as_float(p & 0xffff0000u); }

#define GLOAD_LDS4(g, l)                                                        \
    __builtin_amdgcn_global_load_lds(                                           \
        (__attribute__((address_space(1))) unsigned int*)(g),                   \
        (__attribute__((address_space(3))) unsigned int*)(l), 4, 0, 0)
#define GLOAD_LDS16(g, l)                                                       \
    __builtin_amdgcn_global_load_lds(                                           \
        (__attribute__((address_space(1))) unsigned int*)(g),                   \
        (__attribute__((address_space(3))) unsigned int*)(l), 16, 0, 0)

// ---------------- W transpose + convert + pad: Wt[n][k] = bf16(W[k][n]) ----------------
__global__ __launch_bounds__(256) void prep_wt(const float* __restrict__ W,
                                               unsigned short* __restrict__ Wt,
                                               int K, int N, int KP) {
    __shared__ float t[32][33];
    int k0 = blockIdx.x * 32, n0 = blockIdx.y * 32;
    int tx = threadIdx.x & 31, ty = threadIdx.x >> 5;   // 256 thr: ty 0..7
#pragma unroll
    for (int i = 0; i < 32; i += 8) {
        int k = k0 + ty + i, n = n0 + tx;
        t[ty + i][tx] = (k < K && n < N) ? W[(size_t)k * N + n] : 0.f;
    }
    __syncthreads();
#pragma unroll
    for (int i = 0; i < 32; i += 8) {
        int n = n0 + ty + i, k = k0 + tx;
        Wt[(size_t)n * KP + k] = f2bf(t[tx][ty + i]);
    }
}

// ---------------- bf16 MFMA GEMM ----------------
// C[M][HP](bf16) = A[M][K](f32, stride lda) @ Bt^T  where Bt is [HP][KP] bf16 (pre-transposed, zero-padded)
// tile 128x128, BK=32, 256 threads = 4 waves (2x2), each wave 64x64 out.
__global__ __launch_bounds__(256) void gemm_bf16(const float* __restrict__ A,
                                                 const unsigned short* __restrict__ Bt,
                                                 unsigned short* __restrict__ C,
                                                 int M, int K, int lda, int KP) {
    // As: f32 [128][32], row pitch 128B, 8 slots of 4 words, slot-XOR-swizzled by (r&7)
    // Bs: bf16 [128][32], row pitch 64B, 4 slots of 8 halves, slot-XOR-swizzled by ((n>>1)&3)
    __shared__ float          As[128 * 32];
    __shared__ unsigned short Bs[128 * 32];

    const int tid  = threadIdx.x;
    const int lane = tid & 63;
    const int wv   = tid >> 6;    // 0..3
    const int wr   = wv >> 1;     // wave row 0..1
    const int wc   = wv & 1;      // wave col 0..1
    const int m0   = blockIdx.y * 128;
    const int n0   = blockIdx.x * 128;
    const bool fullM = (m0 + 128 <= M);

    f32x4 acc[4][4] = {};

    const int ksteps = (K + 31) >> 5;

    // staging lane geometry
    const int a_rw    = lane >> 5;        // row-within-pair
    const int a_slotp = (lane >> 2) & 7;  // physical 4-word slot
    const int a_j     = lane & 3;
    const int b_nl    = lane >> 2;        // row within 16-row group
    const int b_cp    = lane & 3;         // physical 16B chunk

    const int koff = lane >> 4;           // 0..3 (k-group)
    const int rl   = lane & 15;

    for (int ks = 0; ks < ksteps; ++ks) {
        const int k0 = ks << 5;
        __syncthreads();   // previous compute done before LDS overwrite

        // ---- stage A (f32) ----
        if (fullM && (k0 + 32 <= K)) {
#pragma unroll
            for (int i = 0; i < 16; ++i) {
                int r    = wv * 32 + 2 * i + a_rw;
                int clog = ((a_slotp ^ (r & 7)) << 2) | a_j;   // source k permuted -> linear LDS holds swizzled layout
                const float* src = A + (size_t)(m0 + r) * lda + (k0 + clog);
                float*       dst = &As[(wv * 32 + 2 * i) * 32];
                GLOAD_LDS4(src, dst);
            }
        } else {
#pragma unroll
            for (int p = 0; p < 16; ++p) {
                int idx  = tid + p * 256;
                int r    = idx >> 5, cp = idx & 31;
                int clog = (((cp >> 2) ^ (r & 7)) << 2) | (cp & 3);
                int m = m0 + r, k = k0 + clog;
                As[idx] = (m < M && k < K) ? A[(size_t)m * lda + k] : 0.f;
            }
        }
        // ---- stage B (bf16, width-16 async) ----
#pragma unroll
        for (int i = 0; i < 2; ++i) {
            int nl = wv * 32 + i * 16 + b_nl;
            int cl = b_cp ^ ((nl >> 1) & 3);
            const unsigned short* src = Bt + (size_t)(n0 + nl) * KP + k0 + cl * 8;
            unsigned short*       dst = &Bs[(wv * 32 + i * 16) * 32];
            GLOAD_LDS16(src, dst);
        }
        __syncthreads();   // compiler drains vmcnt before barrier

        // ---- fragments ----
        s16x8 af[4], bfv[4];
#pragma unroll
        for (int mf = 0; mf < 4; ++mf) {
            int r  = wr * 64 + mf * 16 + rl;
            int s0 = (2 * koff) ^ (r & 7);
            int s1 = (2 * koff + 1) ^ (r & 7);
            f32x4 lo = *(const f32x4*)&As[r * 32 + s0 * 4];
            f32x4 hi = *(const f32x4*)&As[r * 32 + s1 * 4];
            s16x8 t;
            t[0] = (short)f2bf(lo[0]); t[1] = (short)f2bf(lo[1]);
            t[2] = (short)f2bf(lo[2]); t[3] = (short)f2bf(lo[3]);
            t[4] = (short)f2bf(hi[0]); t[5] = (short)f2bf(hi[1]);
            t[6] = (short)f2bf(hi[2]); t[7] = (short)f2bf(hi[3]);
            af[mf] = t;
        }
#pragma unroll
        for (int nf = 0; nf < 4; ++nf) {
            int n  = wc * 64 + nf * 16 + rl;
            int sp = koff ^ ((n >> 1) & 3);
            bfv[nf] = *(const s16x8*)&Bs[n * 32 + sp * 8];
        }
        // ---- 16 MFMAs (builtin: compiler handles MFMA hazards/nops) ----
#pragma unroll
        for (int mf = 0; mf < 4; ++mf)
#pragma unroll
            for (int nf = 0; nf < 4; ++nf)
                acc[mf][nf] = __builtin_amdgcn_mfma_f32_16x16x32_bf16(
                    af[mf], bfv[nf], acc[mf][nf], 0, 0, 0);
    }

    // ---- store C as bf16 (C/D layout: col=lane&15, row=(lane>>4)*4+reg) ----
#pragma unroll
    for (int mf = 0; mf < 4; ++mf) {
#pragma unroll
        for (int nf = 0; nf < 4; ++nf) {
            int col = n0 + wc * 64 + nf * 16 + rl;
#pragma unroll
            for (int j = 0; j < 4; ++j) {
                int row = m0 + wr * 64 + mf * 16 + koff * 4 + j;
                if (row < M) C[(size_t)row * HP + col] = f2bf(acc[mf][nf][j]);
            }
        }
    }
}

// ---------------- CSR build ----------------
__global__ void count_deg(const int* __restrict__ dst, int* __restrict__ deg, int E) {
    int i = blockIdx.x * blockDim.x + threadIdx.x;
    if (i < E) atomicAdd(&deg[dst[i]], 1);
}

__global__ void scan_block(const int* __restrict__ in, int* __restrict__ out,
                           int* __restrict__ bsum, int n) {
    __shared__ int s[256];
    int i = blockIdx.x * 256 + threadIdx.x;
    int v = (i < n) ? in[i] : 0;
    s[threadIdx.x] = v;
    __syncthreads();
    for (int off = 1; off < 256; off <<= 1) {
        int t = (threadIdx.x >= (unsigned)off) ? s[threadIdx.x - off] : 0;
        __syncthreads();
        s[threadIdx.x] += t;
        __syncthreads();
    }
    if (i < n) out[i] = s[threadIdx.x] - v;  // exclusive
    if (bsum && threadIdx.x == 255) bsum[blockIdx.x] = s[255];
}

__global__ void scan_add(int* __restrict__ out, const int* __restrict__ bsum, int n, int E) {
    int i = blockIdx.x * 256 + threadIdx.x;
    if (i < n) out[i] += bsum[blockIdx.x];
    if (i == 0) out[n] = E;
}

__global__ void scatter_edges(const int* __restrict__ dst, const int* __restrict__ offs,
                              int* __restrict__ cursor, int* __restrict__ eid, int E) {
    int e = blockIdx.x * blockDim.x + threadIdx.x;
    if (e < E) {
        int d = dst[e];
        int p = atomicAdd(&cursor[d], 1);
        eid[offs[d] + p] = e;
    }
}

// ---------------- aggregation: out[n][0..511] = relu?( sum_e w*P[src] + bias ), P bf16 ----------------
__global__ __launch_bounds__(256) void aggregate_k(const unsigned short* __restrict__ P,
                                                   const int* __restrict__ offs,
                                                   const int* __restrict__ eid,
                                                   const int* __restrict__ src,
                                                   const float* __restrict__ ew,
                                                   const float* __restrict__ bias,
                                                   float* __restrict__ out,
                                                   int do_relu) {
    int n = blockIdx.x, tid = threadIdx.x;
    int beg = offs[n], end = offs[n + 1];
    float a0 = 0.f, a1 = 0.f;
    for (int i = beg; i < end; ++i) {
        int e = eid[i];
        int s = src[e];
        float w = ew[e];
        unsigned pv = *(const unsigned*)(P + (size_t)s * HP + tid * 2);
        a0 += w * bflo(pv);
        a1 += w * bfhi(pv);
    }
    int c0 = tid * 2, c1 = c0 + 1;
    float v0 = a0 + ((c0 < HIDDEN) ? bias[c0] : 0.f);
    float v1 = a1 + ((c1 < HIDDEN) ? bias[c1] : 0.f);
    if (do_relu) { v0 = fmaxf(v0, 0.f); v1 = fmaxf(v1, 0.f); }
    out[(size_t)n * HP + c0] = v0;
    out[(size_t)n * HP + c1] = v1;
}

// ---------------- layer 3 (stays fp32) ----------------
__global__ void logits_k(const float* __restrict__ H, const float* __restrict__ W3,
                         float* __restrict__ L) {
    int t = blockIdx.x * blockDim.x + threadIdx.x;
    if (t >= N_NODES * N_CLASSES) return;
    int n = t / N_CLASSES, c = t % N_CLASSES;
    const float* row = H + (size_t)n * HP;
    float acc = 0.f;
    for (int k = 0; k < HIDDEN; k++) acc += row[k] * W3[k * N_CLASSES + c];
    L[t] = acc;
}

__global__ void agg_logits(const float* __restrict__ L, const int* __restrict__ src,
                           const int* __restrict__ dst, const float* __restrict__ ew,
                           float* __restrict__ aggL, int E) {
    int e = blockIdx.x * blockDim.x + threadIdx.x;
    if (e >= E) return;
    int s = src[e], d = dst[e];
    float w = ew[e];
#pragma unroll
    for (int c = 0; c < N_CLASSES; c++)
        atomicAdd(&aggL[(size_t)d * N_CLASSES + c], w * L[(size_t)s * N_CLASSES + c]);
}

__global__ void log_softmax_k(const float* __restrict__ aggL, const float* __restrict__ b3,
                              float* __restrict__ out) {
    int n = blockIdx.x * blockDim.x + threadIdx.x;
    if (n >= N_NODES) return;
    float v[N_CLASSES];
    float m = -1e30f;
#pragma unroll
    for (int c = 0; c < N_CLASSES; c++) {
        v[c] = aggL[(size_t)n * N_CLASSES + c] + b3[c];
        m = fmaxf(m, v[c]);
    }
    float s = 0.f;
#pragma unroll
    for (int c = 0; c < N_CLASSES; c++) s += expf(v[c] - m);
    float ls = logf(s) + m;
#pragma unroll
    for (int c = 0; c < N_CLASSES; c++) out[(size_t)n * N_CLASSES + c] = v[c] - ls;
}

// ---------------- launch ----------------
extern "C" void kernel_launch(void* const* d_in, const int* in_sizes, int n_in,
                              void* d_out, int out_size, void* d_ws, size_t ws_size,
                              hipStream_t stream) {
    const float* x   = (const float*)d_in[0];
    const float* w1  = (const float*)d_in[1];
    const float* b1  = (const float*)d_in[2];
    const float* w2  = (const float*)d_in[3];
    const float* b2  = (const float*)d_in[4];
    const float* w3  = (const float*)d_in[5];
    const float* b3  = (const float*)d_in[6];
    const float* ew  = (const float*)d_in[7];
    const int* esrc  = (const int*)d_in[8];
    const int* edst  = (const int*)d_in[9];
    float* out = (float*)d_out;

    char* ws = (char*)d_ws;
    size_t off = 0;
    auto alloc = [&](size_t bytes) {
        void* p = ws + off;
        off += (bytes + 255) & ~(size_t)255;
        return p;
    };
    const int MP = ((N_NODES + 127) / 128) * 128;  // 50048
    unsigned short* Cb  = (unsigned short*)alloc((size_t)MP * HP * 2);  // pre-agg, bf16
    float* bufB         = (float*)alloc((size_t)MP * HP * 4);           // post-agg, f32
    unsigned short* W1t = (unsigned short*)alloc((size_t)HP * KP1 * 2);
    unsigned short* W2t = (unsigned short*)alloc((size_t)HP * HP * 2);
    float* L      = (float*)alloc((size_t)N_NODES * N_CLASSES * 4);
    float* aggL   = (float*)alloc((size_t)N_NODES * N_CLASSES * 4);
    int* deg      = (int*)alloc((size_t)N_NODES * 4);
    int* offs     = (int*)alloc((size_t)(N_NODES + 1) * 4);
    int* cursor   = (int*)alloc((size_t)N_NODES * 4);
    int* bsum     = (int*)alloc(256 * 4);
    int* eid      = (int*)alloc((size_t)N_EDGES * 4);
    (void)ws_size; (void)n_in; (void)in_sizes; (void)out_size;

    const int E = N_EDGES;
    const int nScanBlocks = (N_NODES + 255) / 256;

    hipMemsetAsync(deg, 0, (size_t)N_NODES * 4, stream);
    hipMemsetAsync(cursor, 0, (size_t)N_NODES * 4, stream);
    hipMemsetAsync(aggL, 0, (size_t)N_NODES * N_CLASSES * 4, stream);

    // weight prep (transpose + bf16 + zero-pad)
    prep_wt<<<dim3(KP1 / 32, HP / 32), 256, 0, stream>>>(w1, W1t, IN_DIM, HIDDEN, KP1);
    prep_wt<<<dim3(HP / 32, HP / 32), 256, 0, stream>>>(w2, W2t, HIDDEN, HIDDEN, HP);

    // CSR build
    count_deg<<<(E + 255) / 256, 256, 0, stream>>>(edst, deg, E);
    scan_block<<<nScanBlocks, 256, 0, stream>>>(deg, offs, bsum, N_NODES);
    scan_block<<<1, 256, 0, stream>>>(bsum, bsum, nullptr, nScanBlocks);
    scan_add<<<nScanBlocks, 256, 0, stream>>>(offs, bsum, N_NODES, E);
    scatter_edges<<<(E + 255) / 256, 256, 0, stream>>>(edst, offs, cursor, eid, E);

    // layer 1: Cb = bf16(x @ w1)
    gemm_bf16<<<dim3(HP / 128, MP / 128), 256, 0, stream>>>(x, W1t, Cb, N_NODES, IN_DIM, IN_DIM, KP1);
    aggregate_k<<<N_NODES, 256, 0, stream>>>(Cb, offs, eid, esrc, ew, b1, bufB, 1);

    // layer 2: Cb = bf16(h1 @ w2)   (bufB pad cols are true zeros -> K=HP)
    gemm_bf16<<<dim3(HP / 128, MP / 128), 256, 0, stream>>>(bufB, W2t, Cb, N_NODES, HP, HP, HP);
    aggregate_k<<<N_NODES, 256, 0, stream>>>(Cb, offs, eid, esrc, ew, b2, bufB, 1);

    // layer 3
    logits_k<<<(N_NODES * N_CLASSES + 255) / 256, 256, 0, stream>>>(bufB, w3, L);
    agg_logits<<<(E + 255) / 256, 256, 0, stream>>>(L, esrc, edst, ew, aggL, E);
    log_softmax_k<<<(N_NODES + 255) / 256, 256, 0, stream>>>(aggL, b3, out);
}